// Round 1
// baseline (1894.774 us; speedup 1.0000x reference)
//
#include <hip/hip_runtime.h>
#include <math.h>

#define B_ 2
#define T_ 2048
#define D_ 512
#define H_ 8
#define DH_ 64
#define SCALE_ 0.125f
#define DECAY_ 0.99f

static constexpr size_t QSZ = (size_t)B_ * H_ * T_ * DH_; // 2,097,152 floats

// ---------------- GEMM: C = A @ W^T + bias ----------------
// A: [M,K] row-major, W: [N,K] row-major. MODE 0: C[M,N]. MODE 1: qkv scatter.
template<int MODE>
__global__ __launch_bounds__(256) void gemm_kernel(const float* __restrict__ A,
    const float* __restrict__ W, const float* __restrict__ bias,
    float* __restrict__ C, int M, int N, int K)
{
  constexpr int BM = 128, BN = 128, BK = 16;
  __shared__ float As[BK][BM + 4];
  __shared__ float Ws[BK][BN + 4];
  const int bm = blockIdx.y * BM, bn = blockIdx.x * BN;
  const int tid = threadIdx.x;
  const int tm = (tid >> 4) << 3, tn = (tid & 15) << 3;
  float acc[8][8] = {};
  for (int k0 = 0; k0 < K; k0 += BK) {
    __syncthreads();
#pragma unroll
    for (int i = 0; i < 2; i++) {
      int slot = i * 256 + tid;
      int r = slot >> 2, c = (slot & 3) << 2;
      float4 av = *(const float4*)(A + (size_t)(bm + r) * K + k0 + c);
      As[c + 0][r] = av.x; As[c + 1][r] = av.y; As[c + 2][r] = av.z; As[c + 3][r] = av.w;
      float4 wv = *(const float4*)(W + (size_t)(bn + r) * K + k0 + c);
      Ws[c + 0][r] = wv.x; Ws[c + 1][r] = wv.y; Ws[c + 2][r] = wv.z; Ws[c + 3][r] = wv.w;
    }
    __syncthreads();
#pragma unroll
    for (int kq = 0; kq < BK; ++kq) {
      float a[8], w[8];
      *(float4*)&a[0] = *(const float4*)&As[kq][tm];
      *(float4*)&a[4] = *(const float4*)&As[kq][tm + 4];
      *(float4*)&w[0] = *(const float4*)&Ws[kq][tn];
      *(float4*)&w[4] = *(const float4*)&Ws[kq][tn + 4];
#pragma unroll
      for (int ii = 0; ii < 8; ii++)
#pragma unroll
        for (int jj = 0; jj < 8; jj++)
          acc[ii][jj] = fmaf(a[ii], w[jj], acc[ii][jj]);
    }
  }
  float bv[8];
#pragma unroll
  for (int jj = 0; jj < 8; jj++) bv[jj] = bias[bn + tn + jj];
  if (MODE == 0) {
#pragma unroll
    for (int ii = 0; ii < 8; ii++) {
      size_t base = (size_t)(bm + tm + ii) * N + bn + tn;
      float4 o0, o1;
      o0.x = acc[ii][0] + bv[0]; o0.y = acc[ii][1] + bv[1];
      o0.z = acc[ii][2] + bv[2]; o0.w = acc[ii][3] + bv[3];
      o1.x = acc[ii][4] + bv[4]; o1.y = acc[ii][5] + bv[5];
      o1.z = acc[ii][6] + bv[6]; o1.w = acc[ii][7] + bv[7];
      *(float4*)(C + base) = o0;
      *(float4*)(C + base + 4) = o1;
    }
  } else {
    // qkv scatter: n -> (s, h, dh); write [B,H,T,DH]; q gets SCALE folded in
    int n0 = bn + tn;
    int s = n0 >> 9, h = (n0 >> 6) & 7, dh0 = n0 & 63;
    float scl = (s == 0) ? SCALE_ : 1.0f;
#pragma unroll
    for (int ii = 0; ii < 8; ii++) {
      int m = bm + tm + ii;
      int b = m >> 11, t = m & 2047;
      float* dst = C + (size_t)s * QSZ + (((size_t)(b * H_ + h)) * T_ + t) * DH_ + dh0;
      float4 o0, o1;
      o0.x = (acc[ii][0] + bv[0]) * scl; o0.y = (acc[ii][1] + bv[1]) * scl;
      o0.z = (acc[ii][2] + bv[2]) * scl; o0.w = (acc[ii][3] + bv[3]) * scl;
      o1.x = (acc[ii][4] + bv[4]) * scl; o1.y = (acc[ii][5] + bv[5]) * scl;
      o1.z = (acc[ii][6] + bv[6]) * scl; o1.w = (acc[ii][7] + bv[7]) * scl;
      *(float4*)dst = o0;
      *(float4*)(dst + 4) = o1;
    }
  }
}

// ------------- small projections + Plucker lines + gate -------------
__global__ __launch_bounds__(256) void proj_lines_kernel(
    const float* __restrict__ x,
    const float* __restrict__ w1w, const float* __restrict__ w2w,
    const float* __restrict__ w1r, const float* __restrict__ w2r,
    const float* __restrict__ gw, const float* __restrict__ gb,
    float* __restrict__ u_out,   // [B,H,T,6]  (J-transformed write lines)
    float* __restrict__ r_out,   // [B,H,T,6]
    float* __restrict__ gate_out // [B,T,H]
) {
  int bt = blockIdx.x;
  int b = bt / T_, t = bt % T_;
  __shared__ float xs[D_], xps[D_];
  __shared__ float res[136]; // w1[0:32] w2[32:64] r1[64:96] r2[96:128] gate[128:136]
  int tid = threadIdx.x;
  for (int i = tid; i < D_; i += 256) {
    xs[i] = x[(size_t)(b * T_ + t) * D_ + i];
    xps[i] = (t == 0) ? 0.f : x[(size_t)(b * T_ + t - 1) * D_ + i];
  }
  __syncthreads();
  if (tid < 136) {
    const float* wrow;
    const float* xv = xs;
    float bias = 0.f;
    int n = tid;
    if (n < 32)       { wrow = w1w + (size_t)n * D_; xv = xps; }
    else if (n < 64)  { wrow = w2w + (size_t)(n - 32) * D_; }
    else if (n < 96)  { wrow = w1r + (size_t)(n - 64) * D_; }
    else if (n < 128) { wrow = w2r + (size_t)(n - 96) * D_; }
    else              { wrow = gw + (size_t)(n - 128) * D_; bias = gb[n - 128]; }
    float s = bias;
    for (int k2 = 0; k2 < D_; k2 += 4) {
      float4 wv = *(const float4*)(wrow + k2);
      s = fmaf(xv[k2], wv.x, s);
      s = fmaf(xv[k2 + 1], wv.y, s);
      s = fmaf(xv[k2 + 2], wv.z, s);
      s = fmaf(xv[k2 + 3], wv.w, s);
    }
    res[n] = s;
  }
  __syncthreads();
  if (tid < 16) {
    int h = tid >> 1;
    bool wr = (tid & 1) == 0;
    const float* p1 = wr ? &res[h * 4] : &res[64 + h * 4];
    const float* p2 = wr ? &res[32 + h * 4] : &res[96 + h * 4];
    const int pi[6] = {0, 0, 0, 1, 1, 2};
    const int pj[6] = {1, 2, 3, 2, 3, 3};
    float L[6];
    float n2 = 0.f;
#pragma unroll
    for (int e = 0; e < 6; e++) {
      L[e] = p1[pi[e]] * p2[pj[e]] - p1[pj[e]] * p2[pi[e]];
      n2 = fmaf(L[e], L[e], n2);
    }
    float inv = 1.f / fmaxf(sqrtf(n2), 1e-12f);
    size_t base = (((size_t)(b * H_ + h)) * T_ + t) * 6;
    if (wr) {
      // u = write_lines @ J6: u = (L5, -L4, L3, L2, -L1, L0), normalized
      u_out[base + 0] =  L[5] * inv;
      u_out[base + 1] = -L[4] * inv;
      u_out[base + 2] =  L[3] * inv;
      u_out[base + 3] =  L[2] * inv;
      u_out[base + 4] = -L[1] * inv;
      u_out[base + 5] =  L[0] * inv;
    } else {
#pragma unroll
      for (int e = 0; e < 6; e++) r_out[base + e] = L[e] * inv;
    }
  }
  if (tid >= 16 && tid < 24) {
    int h = tid - 16;
    gate_out[(size_t)(b * T_ + t) * H_ + h] = 1.f / (1.f + __expf(-res[128 + h]));
  }
}

// ------------- flash attention (fp32), one lane per q-row -------------
__global__ __launch_bounds__(64) void attn_kernel(
    const float* __restrict__ q, const float* __restrict__ k,
    const float* __restrict__ v, float* __restrict__ seq_out)
{
  int bh = blockIdx.x, qb = blockIdx.y;
  int lane = threadIdx.x;
  int i = qb * 64 + lane;
  __shared__ float ks[64][64];
  __shared__ float vs[64][64];
  const float* qp = q + ((size_t)bh * T_ + i) * DH_;
  float qr[64];
#pragma unroll
  for (int d = 0; d < 64; d += 4) {
    float4 t4 = *(const float4*)(qp + d);
    qr[d] = t4.x; qr[d + 1] = t4.y; qr[d + 2] = t4.z; qr[d + 3] = t4.w;
  }
  float o[64];
#pragma unroll
  for (int d = 0; d < 64; d++) o[d] = 0.f;
  float m = -1e30f, l = 0.f;
  int ntiles = qb + 1;
  for (int kt = 0; kt < ntiles; ++kt) {
    int j0 = kt * 64;
    __syncthreads();
    {
      const float* kp = k + ((size_t)bh * T_ + j0 + lane) * DH_;
      const float* vp = v + ((size_t)bh * T_ + j0 + lane) * DH_;
#pragma unroll
      for (int d = 0; d < 64; d += 4) {
        *(float4*)&ks[lane][d] = *(const float4*)(kp + d);
        *(float4*)&vs[lane][d] = *(const float4*)(vp + d);
      }
    }
    __syncthreads();
    bool lastTile = (kt == ntiles - 1);
    for (int js = 0; js < 64; js += 8) {
      float s[8];
#pragma unroll
      for (int jj = 0; jj < 8; jj++) s[jj] = 0.f;
#pragma unroll
      for (int d = 0; d < 64; d += 4) {
#pragma unroll
        for (int jj = 0; jj < 8; jj++) {
          float4 kk = *(const float4*)&ks[js + jj][d];
          s[jj] = fmaf(qr[d], kk.x, s[jj]);
          s[jj] = fmaf(qr[d + 1], kk.y, s[jj]);
          s[jj] = fmaf(qr[d + 2], kk.z, s[jj]);
          s[jj] = fmaf(qr[d + 3], kk.w, s[jj]);
        }
      }
      if (lastTile) {
#pragma unroll
        for (int jj = 0; jj < 8; jj++)
          if (j0 + js + jj > i) s[jj] = -1e30f;
      }
      float tmax = m;
#pragma unroll
      for (int jj = 0; jj < 8; jj++) tmax = fmaxf(tmax, s[jj]);
      float alpha = __expf(m - tmax);
      m = tmax;
      float p[8];
      float psum = 0.f;
#pragma unroll
      for (int jj = 0; jj < 8; jj++) { p[jj] = __expf(s[jj] - m); psum += p[jj]; }
      l = l * alpha + psum;
#pragma unroll
      for (int d = 0; d < 64; d++) o[d] *= alpha;
#pragma unroll
      for (int jj = 0; jj < 8; jj++) {
#pragma unroll
        for (int d = 0; d < 64; d += 4) {
          float4 vv = *(const float4*)&vs[js + jj][d];
          o[d] = fmaf(p[jj], vv.x, o[d]);
          o[d + 1] = fmaf(p[jj], vv.y, o[d + 1]);
          o[d + 2] = fmaf(p[jj], vv.z, o[d + 2]);
          o[d + 3] = fmaf(p[jj], vv.w, o[d + 3]);
        }
      }
    }
  }
  float inv = 1.f / l;
  int b = bh / H_, h = bh % H_;
  float* op = seq_out + ((size_t)(b * T_) + i) * D_ + h * DH_;
#pragma unroll
  for (int d = 0; d < 64; d += 4) {
    float4 t4;
    t4.x = o[d] * inv; t4.y = o[d + 1] * inv; t4.z = o[d + 2] * inv; t4.w = o[d + 3] * inv;
    *(float4*)(op + d) = t4;
  }
}

// ------------- memory score: s_i = sum_{j<i} decay^(i-j) (r_i . u_j)^2 -------------
#define CHUNK_ 128
__global__ __launch_bounds__(CHUNK_) void memscore_kernel(
    const float* __restrict__ u, const float* __restrict__ r, float* __restrict__ score)
{
  int bh = blockIdx.x;
  int chunk = blockIdx.y;
  int i0 = chunk * CHUNK_;
  extern __shared__ float us[];
  int jmax = i0 + CHUNK_;
  const float* ub = u + (size_t)bh * T_ * 6;
  for (int idx = threadIdx.x; idx < jmax * 6; idx += CHUNK_) us[idx] = ub[idx];
  __syncthreads();
  int i = i0 + threadIdx.x;
  const float* ri = r + ((size_t)bh * T_ + i) * 6;
  float r0 = ri[0], r1 = ri[1], r2 = ri[2], r3 = ri[3], r4 = ri[4], r5 = ri[5];
  float s = 0.f, w = DECAY_;
  for (int j = i - 1; j >= 0; --j) {
    const float* uj = &us[j * 6];
    float d = r0 * uj[0] + r1 * uj[1] + r2 * uj[2] + r3 * uj[3] + r4 * uj[4] + r5 * uj[5];
    s = fmaf(w, d * d, s);
    w *= DECAY_;
  }
  score[(size_t)bh * T_ + i] = s;
}

// ------------- gating + combine: seqo += mean_h(sig(score*scale)*gate) * mem_val -------------
__global__ __launch_bounds__(256) void gate_combine_kernel(
    const float* __restrict__ score,   // [B,H,T]
    const float* __restrict__ gate,    // [B,T,H]
    const float* __restrict__ mem_scale,
    const float* __restrict__ mem_val, // [B,T,D]
    float* __restrict__ seqo)          // [B,T,D] in/out
{
  int bt = blockIdx.x;
  int b = bt / T_, t = bt % T_;
  __shared__ float g;
  if (threadIdx.x == 0) {
    float acc = 0.f;
#pragma unroll
    for (int h = 0; h < H_; h++) {
      float ms = score[((size_t)(b * H_ + h)) * T_ + t];
      float sg = 1.f / (1.f + __expf(-ms * mem_scale[h]));
      acc += sg * gate[(size_t)(b * T_ + t) * H_ + h];
    }
    g = acc * (1.0f / H_);
  }
  __syncthreads();
  float gv = g;
  size_t base = (size_t)(b * T_ + t) * D_;
  for (int d = threadIdx.x; d < D_; d += 256)
    seqo[base + d] = fmaf(gv, mem_val[base + d], seqo[base + d]);
}

extern "C" void kernel_launch(void* const* d_in, const int* in_sizes, int n_in,
                              void* d_out, int out_size, void* d_ws, size_t ws_size,
                              hipStream_t stream) {
  const float* x     = (const float*)d_in[0];
  const float* qkvw  = (const float*)d_in[1];
  const float* qkvb  = (const float*)d_in[2];
  const float* w1w   = (const float*)d_in[3];
  const float* w2w   = (const float*)d_in[4];
  const float* w1r   = (const float*)d_in[5];
  const float* w2r   = (const float*)d_in[6];
  const float* mvw   = (const float*)d_in[7];
  const float* mvb   = (const float*)d_in[8];
  const float* mgw   = (const float*)d_in[9];
  const float* mgb   = (const float*)d_in[10];
  const float* mscl  = (const float*)d_in[11];
  const float* ow    = (const float*)d_in[12];
  const float* ob    = (const float*)d_in[13];
  (void)in_sizes; (void)n_in; (void)out_size; (void)ws_size;

  float* ws = (float*)d_ws;
  float* q      = ws;               // [B,H,T,DH] (SCALE folded in)
  float* kk     = ws + QSZ;         // [B,H,T,DH]
  float* vv     = ws + 2 * QSZ;     // [B,H,T,DH]
  float* seqo   = ws + 3 * QSZ;     // [B,T,D]
  float* memval = ws + 4 * QSZ;     // [B,T,D]
  float* ul     = ws + 5 * QSZ;                      // [B,H,T,6]
  float* rl     = ul + (size_t)B_ * H_ * T_ * 6;     // [B,H,T,6]
  float* gatep  = rl + (size_t)B_ * H_ * T_ * 6;     // [B,T,H]
  float* msc    = gatep + (size_t)B_ * T_ * H_;      // [B,H,T]

  const int M = B_ * T_;

  gemm_kernel<1><<<dim3(12, 32), 256, 0, stream>>>(x, qkvw, qkvb, ws, M, 3 * D_, D_);
  gemm_kernel<0><<<dim3(4, 32), 256, 0, stream>>>(x, mvw, mvb, memval, M, D_, D_);
  proj_lines_kernel<<<dim3(B_ * T_), 256, 0, stream>>>(x, w1w, w2w, w1r, w2r, mgw, mgb,
                                                       ul, rl, gatep);
  attn_kernel<<<dim3(B_ * H_, T_ / 64), 64, 0, stream>>>(q, kk, vv, seqo);
  memscore_kernel<<<dim3(B_ * H_, T_ / CHUNK_), CHUNK_, T_ * 6 * sizeof(float), stream>>>(
      ul, rl, msc);
  gate_combine_kernel<<<dim3(B_ * T_), 256, 0, stream>>>(msc, gatep, mscl, memval, seqo);
  gemm_kernel<0><<<dim3(4, 32), 256, 0, stream>>>(seqo, ow, ob, (float*)d_out, M, D_, D_);
}

// Round 2
// 505.990 us; speedup vs baseline: 3.7447x; 3.7447x over previous
//
#include <hip/hip_runtime.h>
#include <math.h>

#define B_ 2
#define T_ 2048
#define D_ 512
#define H_ 8
#define DH_ 64
#define SCALE_ 0.125f
#define DECAY_ 0.99f

static constexpr size_t QSZ = (size_t)B_ * H_ * T_ * DH_; // 2,097,152 elems

typedef __bf16 bf16x8 __attribute__((ext_vector_type(8)));
typedef float f32x4 __attribute__((ext_vector_type(4)));

__device__ inline ushort f2bf(float f) {
  uint u = __float_as_uint(f);
  u += 0x7FFF + ((u >> 16) & 1);
  return (ushort)(u >> 16);
}

// ---------------- GEMM: C = A @ W^T + bias ----------------
// A: [M,K] row-major, W: [N,K] row-major.
// MODE 0: C[M,N] fp32.  MODE 1: qkv epilogue -> bf16 q,k [BH,T,64] (+SCALE on q),
//                                bf16 v transposed [BH,64,T].
template<int MODE>
__global__ __launch_bounds__(256) void gemm_kernel(const float* __restrict__ A,
    const float* __restrict__ W, const float* __restrict__ bias,
    float* __restrict__ C, int M, int N, int K)
{
  constexpr int BM = 128, BN = 128, BK = 16;
  __shared__ float As[BK][BM + 4];
  __shared__ float Ws[BK][BN + 4];
  const int bm = blockIdx.y * BM, bn = blockIdx.x * BN;
  const int tid = threadIdx.x;
  const int tm = (tid >> 4) << 3, tn = (tid & 15) << 3;
  float acc[8][8] = {};
  for (int k0 = 0; k0 < K; k0 += BK) {
    __syncthreads();
#pragma unroll
    for (int i = 0; i < 2; i++) {
      int slot = i * 256 + tid;
      int r = slot >> 2, c = (slot & 3) << 2;
      float4 av = *(const float4*)(A + (size_t)(bm + r) * K + k0 + c);
      As[c + 0][r] = av.x; As[c + 1][r] = av.y; As[c + 2][r] = av.z; As[c + 3][r] = av.w;
      float4 wv = *(const float4*)(W + (size_t)(bn + r) * K + k0 + c);
      Ws[c + 0][r] = wv.x; Ws[c + 1][r] = wv.y; Ws[c + 2][r] = wv.z; Ws[c + 3][r] = wv.w;
    }
    __syncthreads();
#pragma unroll
    for (int kq = 0; kq < BK; ++kq) {
      float a[8], w[8];
      *(float4*)&a[0] = *(const float4*)&As[kq][tm];
      *(float4*)&a[4] = *(const float4*)&As[kq][tm + 4];
      *(float4*)&w[0] = *(const float4*)&Ws[kq][tn];
      *(float4*)&w[4] = *(const float4*)&Ws[kq][tn + 4];
#pragma unroll
      for (int ii = 0; ii < 8; ii++)
#pragma unroll
        for (int jj = 0; jj < 8; jj++)
          acc[ii][jj] = fmaf(a[ii], w[jj], acc[ii][jj]);
    }
  }
  float bv[8];
#pragma unroll
  for (int jj = 0; jj < 8; jj++) bv[jj] = bias[bn + tn + jj];
  if (MODE == 0) {
#pragma unroll
    for (int ii = 0; ii < 8; ii++) {
      size_t base = (size_t)(bm + tm + ii) * N + bn + tn;
      float4 o0, o1;
      o0.x = acc[ii][0] + bv[0]; o0.y = acc[ii][1] + bv[1];
      o0.z = acc[ii][2] + bv[2]; o0.w = acc[ii][3] + bv[3];
      o1.x = acc[ii][4] + bv[4]; o1.y = acc[ii][5] + bv[5];
      o1.z = acc[ii][6] + bv[6]; o1.w = acc[ii][7] + bv[7];
      *(float4*)(C + base) = o0;
      *(float4*)(C + base + 4) = o1;
    }
  } else {
    // n -> (s, h, dh). q16 at C, k16 at C+QSZ, vt16 at C+2*QSZ (ushort units)
    ushort* qkv16 = (ushort*)C;
    int n0 = bn + tn;
    int s = n0 >> 9, h = (n0 >> 6) & 7, dh0 = n0 & 63;
    int m0 = bm + tm;
    int b = m0 >> 11, t0q = m0 & 2047;
    size_t bh = (size_t)(b * H_ + h);
    if (s < 2) {
      float scl = (s == 0) ? SCALE_ : 1.0f;
      ushort* base = qkv16 + (size_t)s * QSZ;
#pragma unroll
      for (int ii = 0; ii < 8; ii++) {
        ushort tmp[8];
#pragma unroll
        for (int jj = 0; jj < 8; jj++) tmp[jj] = f2bf((acc[ii][jj] + bv[jj]) * scl);
        *(uint4*)(base + (bh * T_ + t0q + ii) * 64 + dh0) = *(uint4*)tmp;
      }
    } else {
      ushort* vt = qkv16 + 2 * QSZ; // [BH][64][T]
#pragma unroll
      for (int jj = 0; jj < 8; jj++) {
        ushort tmp[8];
#pragma unroll
        for (int ii = 0; ii < 8; ii++) tmp[ii] = f2bf(acc[ii][jj] + bv[jj]);
        *(uint4*)(vt + (bh * 64 + dh0 + jj) * T_ + t0q) = *(uint4*)tmp;
      }
    }
  }
}

// ------------- small projections + Plucker lines + gate -------------
__global__ __launch_bounds__(256) void proj_lines_kernel(
    const float* __restrict__ x,
    const float* __restrict__ w1w, const float* __restrict__ w2w,
    const float* __restrict__ w1r, const float* __restrict__ w2r,
    const float* __restrict__ gw, const float* __restrict__ gb,
    float* __restrict__ u_out,   // [B,H,T,6]  (J-transformed write lines)
    float* __restrict__ r_out,   // [B,H,T,6]
    float* __restrict__ gate_out // [B,T,H]
) {
  int bt = blockIdx.x;
  int b = bt / T_, t = bt % T_;
  __shared__ float xs[D_], xps[D_];
  __shared__ float res[136];
  int tid = threadIdx.x;
  for (int i = tid; i < D_; i += 256) {
    xs[i] = x[(size_t)(b * T_ + t) * D_ + i];
    xps[i] = (t == 0) ? 0.f : x[(size_t)(b * T_ + t - 1) * D_ + i];
  }
  __syncthreads();
  if (tid < 136) {
    const float* wrow;
    const float* xv = xs;
    float bias = 0.f;
    int n = tid;
    if (n < 32)       { wrow = w1w + (size_t)n * D_; xv = xps; }
    else if (n < 64)  { wrow = w2w + (size_t)(n - 32) * D_; }
    else if (n < 96)  { wrow = w1r + (size_t)(n - 64) * D_; }
    else if (n < 128) { wrow = w2r + (size_t)(n - 96) * D_; }
    else              { wrow = gw + (size_t)(n - 128) * D_; bias = gb[n - 128]; }
    float s = bias;
    for (int k2 = 0; k2 < D_; k2 += 4) {
      float4 wv = *(const float4*)(wrow + k2);
      s = fmaf(xv[k2], wv.x, s);
      s = fmaf(xv[k2 + 1], wv.y, s);
      s = fmaf(xv[k2 + 2], wv.z, s);
      s = fmaf(xv[k2 + 3], wv.w, s);
    }
    res[n] = s;
  }
  __syncthreads();
  if (tid < 16) {
    int h = tid >> 1;
    bool wr = (tid & 1) == 0;
    const float* p1 = wr ? &res[h * 4] : &res[64 + h * 4];
    const float* p2 = wr ? &res[32 + h * 4] : &res[96 + h * 4];
    const int pi[6] = {0, 0, 0, 1, 1, 2};
    const int pj[6] = {1, 2, 3, 2, 3, 3};
    float L[6];
    float n2 = 0.f;
#pragma unroll
    for (int e = 0; e < 6; e++) {
      L[e] = p1[pi[e]] * p2[pj[e]] - p1[pj[e]] * p2[pi[e]];
      n2 = fmaf(L[e], L[e], n2);
    }
    float inv = 1.f / fmaxf(sqrtf(n2), 1e-12f);
    size_t base = (((size_t)(b * H_ + h)) * T_ + t) * 6;
    if (wr) {
      u_out[base + 0] =  L[5] * inv;
      u_out[base + 1] = -L[4] * inv;
      u_out[base + 2] =  L[3] * inv;
      u_out[base + 3] =  L[2] * inv;
      u_out[base + 4] = -L[1] * inv;
      u_out[base + 5] =  L[0] * inv;
    } else {
#pragma unroll
      for (int e = 0; e < 6; e++) r_out[base + e] = L[e] * inv;
    }
  }
  if (tid >= 16 && tid < 24) {
    int h = tid - 16;
    gate_out[(size_t)(b * T_ + t) * H_ + h] = 1.f / (1.f + __expf(-res[128 + h]));
  }
}

// ------------- MFMA flash attention (bf16 in, fp32 out) -------------
// 4 waves/block; wave w owns q-rows [qb*64 + w*16, +16). KV tiles of 64.
__global__ __launch_bounds__(256) void attn_mfma_kernel(
    const ushort* __restrict__ q16, const ushort* __restrict__ k16,
    const ushort* __restrict__ vt16, float* __restrict__ seq_out)
{
  const int bh = blockIdx.x & 15;
  const int qb = (T_ / 64 - 1) - (blockIdx.x >> 4);  // heavy blocks first
  const int tid = threadIdx.x;
  const int wave = tid >> 6, lane = tid & 63;
  const int col16 = lane & 15, grp = lane >> 4;

  __shared__ __align__(16) ushort ks_[64][72];       // K tile [j][k], pad->2-way
  __shared__ __align__(16) ushort vs_[64][72];       // V^T tile [d][j]
  __shared__ __align__(16) ushort ps_[4][16][72];    // per-wave P [i][j]

  // Q fragments (A-layout: row=col16, k=grp*8+jj), two 32-wide k-steps
  const int iq = qb * 64 + wave * 16 + col16;
  const ushort* qp = q16 + ((size_t)bh * T_ + iq) * 64 + grp * 8;
  bf16x8 aq0 = *(const bf16x8*)(qp);
  bf16x8 aq1 = *(const bf16x8*)(qp + 32);

  f32x4 o[4] = {};
  float m[4], l[4];
#pragma unroll
  for (int r = 0; r < 4; r++) { m[r] = -1e30f; l[r] = 0.f; }

  const size_t kbase = (size_t)bh * T_ * 64;
  const size_t vbase = (size_t)bh * 64 * T_;

  for (int kt = 0; kt <= qb; ++kt) {
    const int j0 = kt * 64;
    __syncthreads();
#pragma unroll
    for (int c = tid; c < 512; c += 256) {
      int r = c >> 3, cc = (c & 7) * 8;
      *(uint4*)&ks_[r][cc] = *(const uint4*)(k16 + kbase + (size_t)(j0 + r) * 64 + cc);
      *(uint4*)&vs_[r][cc] = *(const uint4*)(vt16 + vbase + (size_t)r * T_ + j0 + cc);
    }
    __syncthreads();

    // S tile: D[i][j], col=j(lane&15), row=i(grp*4+r)
    f32x4 facc[4] = {};
#pragma unroll
    for (int jt = 0; jt < 4; jt++) {
      bf16x8 b0 = *(const bf16x8*)&ks_[jt * 16 + col16][grp * 8];
      facc[jt] = __builtin_amdgcn_mfma_f32_16x16x32_bf16(aq0, b0, facc[jt], 0, 0, 0);
      bf16x8 b1 = *(const bf16x8*)&ks_[jt * 16 + col16][32 + grp * 8];
      facc[jt] = __builtin_amdgcn_mfma_f32_16x16x32_bf16(aq1, b1, facc[jt], 0, 0, 0);
    }
    if (kt == qb) {  // causal mask, diagonal tile only
      const int ib = qb * 64 + wave * 16 + grp * 4;
#pragma unroll
      for (int jt = 0; jt < 4; jt++) {
        int j = j0 + jt * 16 + col16;
#pragma unroll
        for (int r = 0; r < 4; r++)
          if (j > ib + r) facc[jt][r] = -1e30f;
      }
    }
    // online softmax: row r of this group's 4 rows; reduce over 16 lanes
    float alpha[4];
#pragma unroll
    for (int r = 0; r < 4; r++) {
      float mx = fmaxf(fmaxf(facc[0][r], facc[1][r]), fmaxf(facc[2][r], facc[3][r]));
#pragma unroll
      for (int s2 = 1; s2 < 16; s2 <<= 1) mx = fmaxf(mx, __shfl_xor(mx, s2));
      float mn = fmaxf(m[r], mx);
      alpha[r] = __expf(m[r] - mn);
      m[r] = mn;
    }
    float p[4][4];
#pragma unroll
    for (int jt = 0; jt < 4; jt++)
#pragma unroll
      for (int r = 0; r < 4; r++) p[jt][r] = __expf(facc[jt][r] - m[r]);
#pragma unroll
    for (int r = 0; r < 4; r++) {
      float ps = (p[0][r] + p[1][r]) + (p[2][r] + p[3][r]);
#pragma unroll
      for (int s2 = 1; s2 < 16; s2 <<= 1) ps += __shfl_xor(ps, s2);
      l[r] = l[r] * alpha[r] + ps;
    }
#pragma unroll
    for (int n = 0; n < 4; n++)
#pragma unroll
      for (int r = 0; r < 4; r++) o[n][r] *= alpha[r];
    // P -> LDS (bf16) to reach A-frag layout
#pragma unroll
    for (int jt = 0; jt < 4; jt++)
#pragma unroll
      for (int r = 0; r < 4; r++)
        ps_[wave][grp * 4 + r][jt * 16 + col16] = f2bf(p[jt][r]);
    __syncthreads();
    // PV: O[i][d] += P[i][j] * V[j][d];  B[j][d] = vs_[d][j]
#pragma unroll
    for (int ks2 = 0; ks2 < 2; ks2++) {
      bf16x8 a = *(const bf16x8*)&ps_[wave][col16][ks2 * 32 + grp * 8];
#pragma unroll
      for (int n = 0; n < 4; n++) {
        bf16x8 b = *(const bf16x8*)&vs_[n * 16 + col16][ks2 * 32 + grp * 8];
        o[n] = __builtin_amdgcn_mfma_f32_16x16x32_bf16(a, b, o[n], 0, 0, 0);
      }
    }
  }
  const int b = bh >> 3, h = bh & 7;
#pragma unroll
  for (int r = 0; r < 4; r++) {
    float inv = 1.f / l[r];
    int i = qb * 64 + wave * 16 + grp * 4 + r;
    float* op = seq_out + ((size_t)(b * T_) + i) * D_ + h * 64;
#pragma unroll
    for (int n = 0; n < 4; n++)
      op[n * 16 + col16] = o[n][r] * inv;
  }
}

// ------------- memory score: s_i = sum_{j<i} decay^(i-j) (r_i . u_j)^2 -------------
#define CHUNK_ 128
__global__ __launch_bounds__(CHUNK_) void memscore_kernel(
    const float* __restrict__ u, const float* __restrict__ r, float* __restrict__ score)
{
  int bh = blockIdx.x;
  int chunk = blockIdx.y;
  int i0 = chunk * CHUNK_;
  extern __shared__ float us[];
  int jmax = i0 + CHUNK_;
  const float* ub = u + (size_t)bh * T_ * 6;
  for (int idx = threadIdx.x; idx < jmax * 6; idx += CHUNK_) us[idx] = ub[idx];
  __syncthreads();
  int i = i0 + threadIdx.x;
  const float* ri = r + ((size_t)bh * T_ + i) * 6;
  float r0 = ri[0], r1 = ri[1], r2 = ri[2], r3 = ri[3], r4 = ri[4], r5 = ri[5];
  float s = 0.f, w = DECAY_;
  for (int j = i - 1; j >= 0; --j) {
    const float* uj = &us[j * 6];
    float d = r0 * uj[0] + r1 * uj[1] + r2 * uj[2] + r3 * uj[3] + r4 * uj[4] + r5 * uj[5];
    s = fmaf(w, d * d, s);
    w *= DECAY_;
  }
  score[(size_t)bh * T_ + i] = s;
}

// ------------- gating + combine -------------
__global__ __launch_bounds__(256) void gate_combine_kernel(
    const float* __restrict__ score,   // [B,H,T]
    const float* __restrict__ gate,    // [B,T,H]
    const float* __restrict__ mem_scale,
    const float* __restrict__ mem_val, // [B,T,D]
    float* __restrict__ seqo)          // [B,T,D] in/out
{
  int bt = blockIdx.x;
  int b = bt / T_, t = bt % T_;
  __shared__ float g;
  if (threadIdx.x == 0) {
    float acc = 0.f;
#pragma unroll
    for (int h = 0; h < H_; h++) {
      float ms = score[((size_t)(b * H_ + h)) * T_ + t];
      float sg = 1.f / (1.f + __expf(-ms * mem_scale[h]));
      acc += sg * gate[(size_t)(b * T_ + t) * H_ + h];
    }
    g = acc * (1.0f / H_);
  }
  __syncthreads();
  float gv = g;
  size_t base = (size_t)(b * T_ + t) * D_;
  for (int d = threadIdx.x; d < D_; d += 256)
    seqo[base + d] = fmaf(gv, mem_val[base + d], seqo[base + d]);
}

extern "C" void kernel_launch(void* const* d_in, const int* in_sizes, int n_in,
                              void* d_out, int out_size, void* d_ws, size_t ws_size,
                              hipStream_t stream) {
  const float* x     = (const float*)d_in[0];
  const float* qkvw  = (const float*)d_in[1];
  const float* qkvb  = (const float*)d_in[2];
  const float* w1w   = (const float*)d_in[3];
  const float* w2w   = (const float*)d_in[4];
  const float* w1r   = (const float*)d_in[5];
  const float* w2r   = (const float*)d_in[6];
  const float* mvw   = (const float*)d_in[7];
  const float* mvb   = (const float*)d_in[8];
  const float* mgw   = (const float*)d_in[9];
  const float* mgb   = (const float*)d_in[10];
  const float* mscl  = (const float*)d_in[11];
  const float* ow    = (const float*)d_in[12];
  const float* ob    = (const float*)d_in[13];
  (void)in_sizes; (void)n_in; (void)out_size; (void)ws_size;

  float* ws = (float*)d_ws;
  float* seqo   = ws;                                // [B,T,D]   2,097,152
  float* memval = ws + 2097152;                      // [B,T,D]   2,097,152
  float* ul     = ws + 4194304;                      // [B,H,T,6]   196,608
  float* rl     = ul + 196608;                       // [B,H,T,6]   196,608
  float* gatep  = rl + 196608;                       // [B,T,H]      32,768
  float* msc    = gatep + 32768;                     // [B,H,T]      32,768
  ushort* q16   = (ushort*)(msc + 32768);            // [BH,T,64] bf16
  ushort* k16   = q16 + QSZ;                         // [BH,T,64] bf16
  ushort* vt16  = k16 + QSZ;                         // [BH,64,T] bf16

  const int M = B_ * T_;

  gemm_kernel<1><<<dim3(12, 32), 256, 0, stream>>>(x, qkvw, qkvb, (float*)q16, M, 3 * D_, D_);
  gemm_kernel<0><<<dim3(4, 32), 256, 0, stream>>>(x, mvw, mvb, memval, M, D_, D_);
  proj_lines_kernel<<<dim3(B_ * T_), 256, 0, stream>>>(x, w1w, w2w, w1r, w2r, mgw, mgb,
                                                       ul, rl, gatep);
  attn_mfma_kernel<<<dim3(16 * (T_ / 64)), 256, 0, stream>>>(q16, k16, vt16, seqo);
  memscore_kernel<<<dim3(B_ * H_, T_ / CHUNK_), CHUNK_, T_ * 6 * sizeof(float), stream>>>(
      ul, rl, msc);
  gate_combine_kernel<<<dim3(B_ * T_), 256, 0, stream>>>(msc, gatep, mscl, memval, seqo);
  gemm_kernel<0><<<dim3(4, 32), 256, 0, stream>>>(seqo, ow, ob, (float*)d_out, M, D_, D_);
}

// Round 3
// 224.145 us; speedup vs baseline: 8.4534x; 2.2574x over previous
//
#include <hip/hip_runtime.h>
#include <math.h>

#define B_ 2
#define T_ 2048
#define D_ 512
#define H_ 8
#define DH_ 64
#define SCALE_ 0.125f
#define DECAY_ 0.99f

static constexpr size_t QSZ = (size_t)B_ * H_ * T_ * DH_; // 2,097,152 elems

typedef __bf16 bf16x8 __attribute__((ext_vector_type(8)));
typedef float f32x4 __attribute__((ext_vector_type(4)));

__device__ inline ushort f2bf(float f) {
  uint u = __float_as_uint(f);
  u += 0x7FFF + ((u >> 16) & 1);
  return (ushort)(u >> 16);
}

__device__ __forceinline__ void gload16(const ushort* g, ushort* l) {
  __builtin_amdgcn_global_load_lds(
      (const __attribute__((address_space(1))) void*)g,
      (__attribute__((address_space(3))) void*)l, 16, 0, 0);
}

// ---------------- fused fp32 -> bf16 cast ----------------
// dst layout: [x 2097152][qkvw 786432][mvw 262144][ow 262144][wcat 256*512]
__global__ __launch_bounds__(256) void cast_bf16_kernel(
    const float* __restrict__ x, const float* __restrict__ qkvw,
    const float* __restrict__ mvw, const float* __restrict__ ow,
    const float* __restrict__ w1w, const float* __restrict__ w2w,
    const float* __restrict__ w1r, const float* __restrict__ w2r,
    const float* __restrict__ mgw, ushort* __restrict__ dst)
{
  size_t e0 = ((size_t)blockIdx.x * 256 + threadIdx.x) * 8;
  const float* src = nullptr;
  if (e0 < 2097152)      src = x + e0;
  else if (e0 < 2883584) src = qkvw + (e0 - 2097152);
  else if (e0 < 3145728) src = mvw + (e0 - 2883584);
  else if (e0 < 3407872) src = ow + (e0 - 3145728);
  else {
    size_t off = e0 - 3407872;
    int row = (int)(off >> 9), col = (int)(off & 511);
    if (row < 32)       src = w1w + (size_t)row * 512 + col;
    else if (row < 64)  src = w2w + (size_t)(row - 32) * 512 + col;
    else if (row < 96)  src = w1r + (size_t)(row - 64) * 512 + col;
    else if (row < 128) src = w2r + (size_t)(row - 96) * 512 + col;
    else if (row < 136) src = mgw + (size_t)(row - 128) * 512 + col;
    else src = nullptr;
  }
  ushort tmp[8];
  if (src) {
    float4 a = *(const float4*)(src);
    float4 b = *(const float4*)(src + 4);
    tmp[0] = f2bf(a.x); tmp[1] = f2bf(a.y); tmp[2] = f2bf(a.z); tmp[3] = f2bf(a.w);
    tmp[4] = f2bf(b.x); tmp[5] = f2bf(b.y); tmp[6] = f2bf(b.z); tmp[7] = f2bf(b.w);
  } else {
#pragma unroll
    for (int i = 0; i < 8; i++) tmp[i] = 0;
  }
  *(uint4*)(dst + e0) = *(uint4*)tmp;
}

// ---------------- MFMA GEMM: C = A(bf16) @ W(bf16)^T (+bias) ----------------
// A:[M,K] W:[N,K] row-major bf16. BM=BN=128, BK=64, 256 thr, 4 waves (2x2).
// EPI 0: fp32 C + bias. EPI 1: qkv scatter (bf16 q,k + v^T). EPI 2: fp32, no bias.
template<int EPI>
__global__ __launch_bounds__(256) void mfma_gemm(const ushort* __restrict__ A,
    const ushort* __restrict__ W, const float* __restrict__ bias,
    void* __restrict__ Cout, int M, int N, int K)
{
  __shared__ __align__(16) ushort As[128 * 64];
  __shared__ __align__(16) ushort Ws[128 * 64];
  const int tid = threadIdx.x;
  const int wave = tid >> 6, lane = tid & 63;
  const int col16 = lane & 15, grp = lane >> 4;
  const int wr = wave >> 1, wc = wave & 1;
  const int bm = blockIdx.y * 128, bn = blockIdx.x * 128;

  f32x4 acc[4][4] = {};
  const int lrow = lane >> 3, lcol = (lane & 7) * 8;

  for (int k0 = 0; k0 < K; k0 += 64) {
    __syncthreads();
#pragma unroll
    for (int i = 0; i < 4; i++) {
      int q = i * 4 + wave;
      int row = q * 8 + lrow;
      gload16(A + (size_t)(bm + row) * K + k0 + lcol, &As[q * 512]);
      gload16(W + (size_t)(bn + row) * K + k0 + lcol, &Ws[q * 512]);
    }
    __syncthreads();
#pragma unroll
    for (int kk = 0; kk < 2; kk++) {
      bf16x8 a[4], b[4];
#pragma unroll
      for (int m = 0; m < 4; m++)
        a[m] = *(const bf16x8*)&As[(wr * 64 + m * 16 + col16) * 64 + kk * 32 + grp * 8];
#pragma unroll
      for (int n = 0; n < 4; n++)
        b[n] = *(const bf16x8*)&Ws[(wc * 64 + n * 16 + col16) * 64 + kk * 32 + grp * 8];
#pragma unroll
      for (int m = 0; m < 4; m++)
#pragma unroll
        for (int n = 0; n < 4; n++)
          acc[m][n] = __builtin_amdgcn_mfma_f32_16x16x32_bf16(a[m], b[n], acc[m][n], 0, 0, 0);
    }
  }

  if (EPI == 1) {
    ushort* q16 = (ushort*)Cout;
    ushort* k16 = q16 + QSZ;
    ushort* vt  = q16 + 2 * QSZ;
#pragma unroll
    for (int n = 0; n < 4; n++) {
      int col = bn + wc * 64 + n * 16 + col16;
      int s = col >> 9, h = (col >> 6) & 7, dh = col & 63;
      float bv = bias[col];
#pragma unroll
      for (int m = 0; m < 4; m++) {
#pragma unroll
        for (int r = 0; r < 4; r++) {
          int row = bm + wr * 64 + m * 16 + grp * 4 + r;
          int b = row >> 11, t = row & 2047;
          float val = acc[m][n][r] + bv;
          size_t bh = (size_t)(b * H_ + h);
          if (s == 0)      q16[(bh * T_ + t) * 64 + dh] = f2bf(val * SCALE_);
          else if (s == 1) k16[(bh * T_ + t) * 64 + dh] = f2bf(val);
          else             vt[(bh * 64 + dh) * T_ + t] = f2bf(val);
        }
      }
    }
  } else {
    float* C = (float*)Cout;
#pragma unroll
    for (int n = 0; n < 4; n++) {
      int col = bn + wc * 64 + n * 16 + col16;
      float bv = (EPI == 0) ? bias[col] : 0.f;
#pragma unroll
      for (int m = 0; m < 4; m++) {
#pragma unroll
        for (int r = 0; r < 4; r++) {
          int row = bm + wr * 64 + m * 16 + grp * 4 + r;
          C[(size_t)row * N + col] = acc[m][n][r] + bv;
        }
      }
    }
  }
}

// ------------- exterior lines + gate from proj rows -------------
// proj: [B*T, 256] fp32 = x @ Wcat^T  (cols: w1 0-31 | w2 32-63 | r1 64-95 | r2 96-127 | gate 128-135)
__global__ __launch_bounds__(256) void lines_kernel(
    const float* __restrict__ proj, const float* __restrict__ gb,
    float* __restrict__ u_out, float* __restrict__ r_out, float* __restrict__ gate_out)
{
  int gid = blockIdx.x * 256 + threadIdx.x;
  int bt = gid >> 3, h = gid & 7;
  int b = bt >> 11, t = bt & 2047;
  const float* pr = proj + (size_t)bt * 256;
  const int pi[6] = {0, 0, 0, 1, 1, 2};
  const int pj[6] = {1, 2, 3, 2, 3, 3};
  float p1[4], p2[4];
  // write line: p1 = proj[t-1] w1-slice (x_prev), p2 = proj[t] w2-slice
#pragma unroll
  for (int e = 0; e < 4; e++) {
    p1[e] = (t == 0) ? 0.f : proj[(size_t)(bt - 1) * 256 + h * 4 + e];
    p2[e] = pr[32 + h * 4 + e];
  }
  float L[6], n2 = 0.f;
#pragma unroll
  for (int e = 0; e < 6; e++) {
    L[e] = p1[pi[e]] * p2[pj[e]] - p1[pj[e]] * p2[pi[e]];
    n2 = fmaf(L[e], L[e], n2);
  }
  float inv = 1.f / fmaxf(sqrtf(n2), 1e-12f);
  size_t base = (((size_t)(b * H_ + h)) * T_ + t) * 6;
  u_out[base + 0] =  L[5] * inv;
  u_out[base + 1] = -L[4] * inv;
  u_out[base + 2] =  L[3] * inv;
  u_out[base + 3] =  L[2] * inv;
  u_out[base + 4] = -L[1] * inv;
  u_out[base + 5] =  L[0] * inv;
  // read line
#pragma unroll
  for (int e = 0; e < 4; e++) {
    p1[e] = pr[64 + h * 4 + e];
    p2[e] = pr[96 + h * 4 + e];
  }
  n2 = 0.f;
#pragma unroll
  for (int e = 0; e < 6; e++) {
    L[e] = p1[pi[e]] * p2[pj[e]] - p1[pj[e]] * p2[pi[e]];
    n2 = fmaf(L[e], L[e], n2);
  }
  inv = 1.f / fmaxf(sqrtf(n2), 1e-12f);
#pragma unroll
  for (int e = 0; e < 6; e++) r_out[base + e] = L[e] * inv;
  // gate
  gate_out[(size_t)bt * H_ + h] = 1.f / (1.f + __expf(-(pr[128 + h] + gb[h])));
}

// ------------- MFMA flash attention (bf16 in, fp32 out) -------------
__global__ __launch_bounds__(256) void attn_mfma_kernel(
    const ushort* __restrict__ q16, const ushort* __restrict__ k16,
    const ushort* __restrict__ vt16, float* __restrict__ seq_out)
{
  const int bh = blockIdx.x & 15;
  const int qb = (T_ / 64 - 1) - (blockIdx.x >> 4);  // heavy blocks first
  const int tid = threadIdx.x;
  const int wave = tid >> 6, lane = tid & 63;
  const int col16 = lane & 15, grp = lane >> 4;

  __shared__ __align__(16) ushort ks_[64][72];
  __shared__ __align__(16) ushort vs_[64][72];
  __shared__ __align__(16) ushort ps_[4][16][72];

  const int iq = qb * 64 + wave * 16 + col16;
  const ushort* qp = q16 + ((size_t)bh * T_ + iq) * 64 + grp * 8;
  bf16x8 aq0 = *(const bf16x8*)(qp);
  bf16x8 aq1 = *(const bf16x8*)(qp + 32);

  f32x4 o[4] = {};
  float m[4], l[4];
#pragma unroll
  for (int r = 0; r < 4; r++) { m[r] = -1e30f; l[r] = 0.f; }

  const size_t kbase = (size_t)bh * T_ * 64;
  const size_t vbase = (size_t)bh * 64 * T_;

  for (int kt = 0; kt <= qb; ++kt) {
    const int j0 = kt * 64;
    __syncthreads();
#pragma unroll
    for (int c = tid; c < 512; c += 256) {
      int r = c >> 3, cc = (c & 7) * 8;
      *(uint4*)&ks_[r][cc] = *(const uint4*)(k16 + kbase + (size_t)(j0 + r) * 64 + cc);
      *(uint4*)&vs_[r][cc] = *(const uint4*)(vt16 + vbase + (size_t)r * T_ + j0 + cc);
    }
    __syncthreads();

    f32x4 facc[4] = {};
#pragma unroll
    for (int jt = 0; jt < 4; jt++) {
      bf16x8 b0 = *(const bf16x8*)&ks_[jt * 16 + col16][grp * 8];
      facc[jt] = __builtin_amdgcn_mfma_f32_16x16x32_bf16(aq0, b0, facc[jt], 0, 0, 0);
      bf16x8 b1 = *(const bf16x8*)&ks_[jt * 16 + col16][32 + grp * 8];
      facc[jt] = __builtin_amdgcn_mfma_f32_16x16x32_bf16(aq1, b1, facc[jt], 0, 0, 0);
    }
    if (kt == qb) {
      const int ib = qb * 64 + wave * 16 + grp * 4;
#pragma unroll
      for (int jt = 0; jt < 4; jt++) {
        int j = j0 + jt * 16 + col16;
#pragma unroll
        for (int r = 0; r < 4; r++)
          if (j > ib + r) facc[jt][r] = -1e30f;
      }
    }
    float alpha[4];
#pragma unroll
    for (int r = 0; r < 4; r++) {
      float mx = fmaxf(fmaxf(facc[0][r], facc[1][r]), fmaxf(facc[2][r], facc[3][r]));
#pragma unroll
      for (int s2 = 1; s2 < 16; s2 <<= 1) mx = fmaxf(mx, __shfl_xor(mx, s2));
      float mn = fmaxf(m[r], mx);
      alpha[r] = __expf(m[r] - mn);
      m[r] = mn;
    }
    float p[4][4];
#pragma unroll
    for (int jt = 0; jt < 4; jt++)
#pragma unroll
      for (int r = 0; r < 4; r++) p[jt][r] = __expf(facc[jt][r] - m[r]);
#pragma unroll
    for (int r = 0; r < 4; r++) {
      float ps = (p[0][r] + p[1][r]) + (p[2][r] + p[3][r]);
#pragma unroll
      for (int s2 = 1; s2 < 16; s2 <<= 1) ps += __shfl_xor(ps, s2);
      l[r] = l[r] * alpha[r] + ps;
    }
#pragma unroll
    for (int n = 0; n < 4; n++)
#pragma unroll
      for (int r = 0; r < 4; r++) o[n][r] *= alpha[r];
#pragma unroll
    for (int jt = 0; jt < 4; jt++)
#pragma unroll
      for (int r = 0; r < 4; r++)
        ps_[wave][grp * 4 + r][jt * 16 + col16] = f2bf(p[jt][r]);
    __syncthreads();
#pragma unroll
    for (int ks2 = 0; ks2 < 2; ks2++) {
      bf16x8 a = *(const bf16x8*)&ps_[wave][col16][ks2 * 32 + grp * 8];
#pragma unroll
      for (int n = 0; n < 4; n++) {
        bf16x8 b = *(const bf16x8*)&vs_[n * 16 + col16][ks2 * 32 + grp * 8];
        o[n] = __builtin_amdgcn_mfma_f32_16x16x32_bf16(a, b, o[n], 0, 0, 0);
      }
    }
  }
  const int b = bh >> 3, h = bh & 7;
#pragma unroll
  for (int r = 0; r < 4; r++) {
    float inv = 1.f / l[r];
    int i = qb * 64 + wave * 16 + grp * 4 + r;
    float* op = seq_out + ((size_t)(b * T_) + i) * D_ + h * 64;
#pragma unroll
    for (int n = 0; n < 4; n++)
      op[n * 16 + col16] = o[n][r] * inv;
  }
}

// ------------- memory score -------------
#define CHUNK_ 128
__global__ __launch_bounds__(CHUNK_) void memscore_kernel(
    const float* __restrict__ u, const float* __restrict__ r, float* __restrict__ score)
{
  int bh = blockIdx.x;
  int chunk = blockIdx.y;
  int i0 = chunk * CHUNK_;
  extern __shared__ float us[];
  int jmax = i0 + CHUNK_;
  const float* ub = u + (size_t)bh * T_ * 6;
  for (int idx = threadIdx.x; idx < jmax * 6; idx += CHUNK_) us[idx] = ub[idx];
  __syncthreads();
  int i = i0 + threadIdx.x;
  const float* ri = r + ((size_t)bh * T_ + i) * 6;
  float r0 = ri[0], r1 = ri[1], r2 = ri[2], r3 = ri[3], r4 = ri[4], r5 = ri[5];
  float s = 0.f, w = DECAY_;
  for (int j = i - 1; j >= 0; --j) {
    const float* uj = &us[j * 6];
    float d = r0 * uj[0] + r1 * uj[1] + r2 * uj[2] + r3 * uj[3] + r4 * uj[4] + r5 * uj[5];
    s = fmaf(w, d * d, s);
    w *= DECAY_;
  }
  score[(size_t)bh * T_ + i] = s;
}

// ------------- gating + combine -> bf16 seqo -------------
__global__ __launch_bounds__(256) void gate_combine_kernel(
    const float* __restrict__ score, const float* __restrict__ gate,
    const float* __restrict__ mem_scale, const float* __restrict__ mem_val,
    const float* __restrict__ seqo, ushort* __restrict__ seqo16)
{
  int bt = blockIdx.x;
  int b = bt / T_, t = bt % T_;
  __shared__ float g;
  if (threadIdx.x == 0) {
    float acc = 0.f;
#pragma unroll
    for (int h = 0; h < H_; h++) {
      float ms = score[((size_t)(b * H_ + h)) * T_ + t];
      float sg = 1.f / (1.f + __expf(-ms * mem_scale[h]));
      acc += sg * gate[(size_t)(b * T_ + t) * H_ + h];
    }
    g = acc * (1.0f / H_);
  }
  __syncthreads();
  float gv = g;
  size_t base = (size_t)(b * T_ + t) * D_;
  for (int d = threadIdx.x; d < D_; d += 256)
    seqo16[base + d] = f2bf(fmaf(gv, mem_val[base + d], seqo[base + d]));
}

extern "C" void kernel_launch(void* const* d_in, const int* in_sizes, int n_in,
                              void* d_out, int out_size, void* d_ws, size_t ws_size,
                              hipStream_t stream) {
  const float* x     = (const float*)d_in[0];
  const float* qkvw  = (const float*)d_in[1];
  const float* qkvb  = (const float*)d_in[2];
  const float* w1w   = (const float*)d_in[3];
  const float* w2w   = (const float*)d_in[4];
  const float* w1r   = (const float*)d_in[5];
  const float* w2r   = (const float*)d_in[6];
  const float* mvw   = (const float*)d_in[7];
  const float* mvb   = (const float*)d_in[8];
  const float* mgw   = (const float*)d_in[9];
  const float* mgb   = (const float*)d_in[10];
  const float* mscl  = (const float*)d_in[11];
  const float* ow    = (const float*)d_in[12];
  const float* ob    = (const float*)d_in[13];
  (void)in_sizes; (void)n_in; (void)out_size; (void)ws_size;

  float* f = (float*)d_ws;
  float* seqo   = f;                      // 2,097,152
  float* memval = seqo + 2097152;         // 2,097,152
  float* proj   = memval + 2097152;       // [4096][256] 1,048,576
  float* ul     = proj + 1048576;         // 196,608
  float* rl     = ul + 196608;            // 196,608
  float* gatep  = rl + 196608;            // 32,768
  float* msc    = gatep + 32768;          // 32,768
  ushort* x16    = (ushort*)(msc + 32768); // 2,097,152 (reused as seqo16 later)
  ushort* qkvw16 = x16 + 2097152;          // 786,432
  ushort* mvw16  = qkvw16 + 786432;        // 262,144
  ushort* ow16   = mvw16 + 262144;         // 262,144
  ushort* wcat16 = ow16 + 262144;          // 131,072
  ushort* q16    = wcat16 + 131072;        // 2,097,152
  ushort* k16    = q16 + QSZ;              // 2,097,152
  ushort* vt16   = k16 + QSZ;              // 2,097,152
  ushort* seqo16 = x16;                    // alias: x16 dead after proj gemm

  const int M = B_ * T_;

  cast_bf16_kernel<<<dim3(1728), 256, 0, stream>>>(x, qkvw, mvw, ow,
                                                   w1w, w2w, w1r, w2r, mgw, x16);
  mfma_gemm<1><<<dim3(12, 32), 256, 0, stream>>>(x16, qkvw16, qkvb, q16, M, 3 * D_, D_);
  mfma_gemm<0><<<dim3(4, 32), 256, 0, stream>>>(x16, mvw16, mvb, memval, M, D_, D_);
  mfma_gemm<2><<<dim3(2, 32), 256, 0, stream>>>(x16, wcat16, nullptr, proj, M, 256, D_);
  lines_kernel<<<dim3(128), 256, 0, stream>>>(proj, mgb, ul, rl, gatep);
  attn_mfma_kernel<<<dim3(16 * (T_ / 64)), 256, 0, stream>>>(q16, k16, vt16, seqo);
  memscore_kernel<<<dim3(B_ * H_, T_ / CHUNK_), CHUNK_, T_ * 6 * sizeof(float), stream>>>(
      ul, rl, msc);
  gate_combine_kernel<<<dim3(B_ * T_), 256, 0, stream>>>(msc, gatep, mscl, memval,
                                                         seqo, seqo16);
  mfma_gemm<0><<<dim3(4, 32), 256, 0, stream>>>(seqo16, ow16, ob, d_out, M, D_, D_);
}

// Round 4
// 205.364 us; speedup vs baseline: 9.2264x; 1.0915x over previous
//
#include <hip/hip_runtime.h>
#include <math.h>

#define B_ 2
#define T_ 2048
#define D_ 512
#define H_ 8
#define DH_ 64
#define SCALE_ 0.125f
#define DECAY_ 0.99f

static constexpr size_t QSZ = (size_t)B_ * H_ * T_ * DH_; // 2,097,152 elems

typedef __bf16 bf16x8 __attribute__((ext_vector_type(8)));
typedef float f32x4 __attribute__((ext_vector_type(4)));

__device__ inline ushort f2bf(float f) {
  uint u = __float_as_uint(f);
  u += 0x7FFF + ((u >> 16) & 1);
  return (ushort)(u >> 16);
}

__device__ __forceinline__ void gload16(const ushort* g, ushort* l) {
  __builtin_amdgcn_global_load_lds(
      (const __attribute__((address_space(1))) void*)g,
      (__attribute__((address_space(3))) void*)l, 16, 0, 0);
}

// ---------------- fused fp32 -> bf16 cast ----------------
__global__ __launch_bounds__(256) void cast_bf16_kernel(
    const float* __restrict__ x, const float* __restrict__ qkvw,
    const float* __restrict__ mvw, const float* __restrict__ ow,
    const float* __restrict__ w1w, const float* __restrict__ w2w,
    const float* __restrict__ w1r, const float* __restrict__ w2r,
    const float* __restrict__ mgw, ushort* __restrict__ dst)
{
  size_t e0 = ((size_t)blockIdx.x * 256 + threadIdx.x) * 8;
  const float* src = nullptr;
  if (e0 < 2097152)      src = x + e0;
  else if (e0 < 2883584) src = qkvw + (e0 - 2097152);
  else if (e0 < 3145728) src = mvw + (e0 - 2883584);
  else if (e0 < 3407872) src = ow + (e0 - 3145728);
  else {
    size_t off = e0 - 3407872;
    int row = (int)(off >> 9), col = (int)(off & 511);
    if (row < 32)       src = w1w + (size_t)row * 512 + col;
    else if (row < 64)  src = w2w + (size_t)(row - 32) * 512 + col;
    else if (row < 96)  src = w1r + (size_t)(row - 64) * 512 + col;
    else if (row < 128) src = w2r + (size_t)(row - 96) * 512 + col;
    else if (row < 136) src = mgw + (size_t)(row - 128) * 512 + col;
    else src = nullptr;
  }
  ushort tmp[8];
  if (src) {
    float4 a = *(const float4*)(src);
    float4 b = *(const float4*)(src + 4);
    tmp[0] = f2bf(a.x); tmp[1] = f2bf(a.y); tmp[2] = f2bf(a.z); tmp[3] = f2bf(a.w);
    tmp[4] = f2bf(b.x); tmp[5] = f2bf(b.y); tmp[6] = f2bf(b.z); tmp[7] = f2bf(b.w);
  } else {
#pragma unroll
    for (int i = 0; i < 8; i++) tmp[i] = 0;
  }
  *(uint4*)(dst + e0) = *(uint4*)tmp;
}

// ---------------- MFMA GEMM: C = A(bf16) @ W(bf16)^T (+bias) ----------------
template<int EPI>
__global__ __launch_bounds__(256) void mfma_gemm(const ushort* __restrict__ A,
    const ushort* __restrict__ W, const float* __restrict__ bias,
    void* __restrict__ Cout, int M, int N, int K)
{
  __shared__ __align__(16) ushort As[128 * 64];
  __shared__ __align__(16) ushort Ws[128 * 64];
  const int tid = threadIdx.x;
  const int wave = tid >> 6, lane = tid & 63;
  const int col16 = lane & 15, grp = lane >> 4;
  const int wr = wave >> 1, wc = wave & 1;
  const int bm = blockIdx.y * 128, bn = blockIdx.x * 128;

  f32x4 acc[4][4] = {};
  const int lrow = lane >> 3, lcol = (lane & 7) * 8;

  for (int k0 = 0; k0 < K; k0 += 64) {
    __syncthreads();
#pragma unroll
    for (int i = 0; i < 4; i++) {
      int q = i * 4 + wave;
      int row = q * 8 + lrow;
      gload16(A + (size_t)(bm + row) * K + k0 + lcol, &As[q * 512]);
      gload16(W + (size_t)(bn + row) * K + k0 + lcol, &Ws[q * 512]);
    }
    __syncthreads();
#pragma unroll
    for (int kk = 0; kk < 2; kk++) {
      bf16x8 a[4], b[4];
#pragma unroll
      for (int m = 0; m < 4; m++)
        a[m] = *(const bf16x8*)&As[(wr * 64 + m * 16 + col16) * 64 + kk * 32 + grp * 8];
#pragma unroll
      for (int n = 0; n < 4; n++)
        b[n] = *(const bf16x8*)&Ws[(wc * 64 + n * 16 + col16) * 64 + kk * 32 + grp * 8];
#pragma unroll
      for (int m = 0; m < 4; m++)
#pragma unroll
        for (int n = 0; n < 4; n++)
          acc[m][n] = __builtin_amdgcn_mfma_f32_16x16x32_bf16(a[m], b[n], acc[m][n], 0, 0, 0);
    }
  }

  if (EPI == 1) {
    ushort* q16 = (ushort*)Cout;
    ushort* k16 = q16 + QSZ;
    ushort* vt  = q16 + 2 * QSZ;
#pragma unroll
    for (int n = 0; n < 4; n++) {
      int col = bn + wc * 64 + n * 16 + col16;
      int s = col >> 9, h = (col >> 6) & 7, dh = col & 63;
      float bv = bias[col];
#pragma unroll
      for (int m = 0; m < 4; m++) {
#pragma unroll
        for (int r = 0; r < 4; r++) {
          int row = bm + wr * 64 + m * 16 + grp * 4 + r;
          int b = row >> 11, t = row & 2047;
          float val = acc[m][n][r] + bv;
          size_t bh = (size_t)(b * H_ + h);
          if (s == 0)      q16[(bh * T_ + t) * 64 + dh] = f2bf(val * SCALE_);
          else if (s == 1) k16[(bh * T_ + t) * 64 + dh] = f2bf(val);
          else             vt[(bh * 64 + dh) * T_ + t] = f2bf(val);
        }
      }
    }
  } else {
    float* C = (float*)Cout;
#pragma unroll
    for (int n = 0; n < 4; n++) {
      int col = bn + wc * 64 + n * 16 + col16;
      float bv = (EPI == 0) ? bias[col] : 0.f;
#pragma unroll
      for (int m = 0; m < 4; m++) {
#pragma unroll
        for (int r = 0; r < 4; r++) {
          int row = bm + wr * 64 + m * 16 + grp * 4 + r;
          C[(size_t)row * N + col] = acc[m][n][r] + bv;
        }
      }
    }
  }
}

// ------------- exterior lines + gate from proj rows -------------
__global__ __launch_bounds__(256) void lines_kernel(
    const float* __restrict__ proj, const float* __restrict__ gb,
    float* __restrict__ u_out, float* __restrict__ r_out, float* __restrict__ gate_out)
{
  int gid = blockIdx.x * 256 + threadIdx.x;
  int bt = gid >> 3, h = gid & 7;
  int b = bt >> 11, t = bt & 2047;
  const float* pr = proj + (size_t)bt * 256;
  const int pi[6] = {0, 0, 0, 1, 1, 2};
  const int pj[6] = {1, 2, 3, 2, 3, 3};
  float p1[4], p2[4];
#pragma unroll
  for (int e = 0; e < 4; e++) {
    p1[e] = (t == 0) ? 0.f : proj[(size_t)(bt - 1) * 256 + h * 4 + e];
    p2[e] = pr[32 + h * 4 + e];
  }
  float L[6], n2 = 0.f;
#pragma unroll
  for (int e = 0; e < 6; e++) {
    L[e] = p1[pi[e]] * p2[pj[e]] - p1[pj[e]] * p2[pi[e]];
    n2 = fmaf(L[e], L[e], n2);
  }
  float inv = 1.f / fmaxf(sqrtf(n2), 1e-12f);
  size_t base = (((size_t)(b * H_ + h)) * T_ + t) * 6;
  u_out[base + 0] =  L[5] * inv;
  u_out[base + 1] = -L[4] * inv;
  u_out[base + 2] =  L[3] * inv;
  u_out[base + 3] =  L[2] * inv;
  u_out[base + 4] = -L[1] * inv;
  u_out[base + 5] =  L[0] * inv;
#pragma unroll
  for (int e = 0; e < 4; e++) {
    p1[e] = pr[64 + h * 4 + e];
    p2[e] = pr[96 + h * 4 + e];
  }
  n2 = 0.f;
#pragma unroll
  for (int e = 0; e < 6; e++) {
    L[e] = p1[pi[e]] * p2[pj[e]] - p1[pj[e]] * p2[pi[e]];
    n2 = fmaf(L[e], L[e], n2);
  }
  inv = 1.f / fmaxf(sqrtf(n2), 1e-12f);
#pragma unroll
  for (int e = 0; e < 6; e++) r_out[base + e] = L[e] * inv;
  gate_out[(size_t)bt * H_ + h] = 1.f / (1.f + __expf(-(pr[128 + h] + gb[h])));
}

// ------------- MFMA flash attention (bf16 in, fp32 out) -------------
__global__ __launch_bounds__(256) void attn_mfma_kernel(
    const ushort* __restrict__ q16, const ushort* __restrict__ k16,
    const ushort* __restrict__ vt16, float* __restrict__ seq_out)
{
  const int bh = blockIdx.x & 15;
  const int qb = (T_ / 64 - 1) - (blockIdx.x >> 4);
  const int tid = threadIdx.x;
  const int wave = tid >> 6, lane = tid & 63;
  const int col16 = lane & 15, grp = lane >> 4;

  __shared__ __align__(16) ushort ks_[64][72];
  __shared__ __align__(16) ushort vs_[64][72];
  __shared__ __align__(16) ushort ps_[4][16][72];

  const int iq = qb * 64 + wave * 16 + col16;
  const ushort* qp = q16 + ((size_t)bh * T_ + iq) * 64 + grp * 8;
  bf16x8 aq0 = *(const bf16x8*)(qp);
  bf16x8 aq1 = *(const bf16x8*)(qp + 32);

  f32x4 o[4] = {};
  float m[4], l[4];
#pragma unroll
  for (int r = 0; r < 4; r++) { m[r] = -1e30f; l[r] = 0.f; }

  const size_t kbase = (size_t)bh * T_ * 64;
  const size_t vbase = (size_t)bh * 64 * T_;

  for (int kt = 0; kt <= qb; ++kt) {
    const int j0 = kt * 64;
    __syncthreads();
#pragma unroll
    for (int c = tid; c < 512; c += 256) {
      int r = c >> 3, cc = (c & 7) * 8;
      *(uint4*)&ks_[r][cc] = *(const uint4*)(k16 + kbase + (size_t)(j0 + r) * 64 + cc);
      *(uint4*)&vs_[r][cc] = *(const uint4*)(vt16 + vbase + (size_t)r * T_ + j0 + cc);
    }
    __syncthreads();

    f32x4 facc[4] = {};
#pragma unroll
    for (int jt = 0; jt < 4; jt++) {
      bf16x8 b0 = *(const bf16x8*)&ks_[jt * 16 + col16][grp * 8];
      facc[jt] = __builtin_amdgcn_mfma_f32_16x16x32_bf16(aq0, b0, facc[jt], 0, 0, 0);
      bf16x8 b1 = *(const bf16x8*)&ks_[jt * 16 + col16][32 + grp * 8];
      facc[jt] = __builtin_amdgcn_mfma_f32_16x16x32_bf16(aq1, b1, facc[jt], 0, 0, 0);
    }
    if (kt == qb) {
      const int ib = qb * 64 + wave * 16 + grp * 4;
#pragma unroll
      for (int jt = 0; jt < 4; jt++) {
        int j = j0 + jt * 16 + col16;
#pragma unroll
        for (int r = 0; r < 4; r++)
          if (j > ib + r) facc[jt][r] = -1e30f;
      }
    }
    float alpha[4];
#pragma unroll
    for (int r = 0; r < 4; r++) {
      float mx = fmaxf(fmaxf(facc[0][r], facc[1][r]), fmaxf(facc[2][r], facc[3][r]));
#pragma unroll
      for (int s2 = 1; s2 < 16; s2 <<= 1) mx = fmaxf(mx, __shfl_xor(mx, s2));
      float mn = fmaxf(m[r], mx);
      alpha[r] = __expf(m[r] - mn);
      m[r] = mn;
    }
    float p[4][4];
#pragma unroll
    for (int jt = 0; jt < 4; jt++)
#pragma unroll
      for (int r = 0; r < 4; r++) p[jt][r] = __expf(facc[jt][r] - m[r]);
#pragma unroll
    for (int r = 0; r < 4; r++) {
      float ps = (p[0][r] + p[1][r]) + (p[2][r] + p[3][r]);
#pragma unroll
      for (int s2 = 1; s2 < 16; s2 <<= 1) ps += __shfl_xor(ps, s2);
      l[r] = l[r] * alpha[r] + ps;
    }
#pragma unroll
    for (int n = 0; n < 4; n++)
#pragma unroll
      for (int r = 0; r < 4; r++) o[n][r] *= alpha[r];
#pragma unroll
    for (int jt = 0; jt < 4; jt++)
#pragma unroll
      for (int r = 0; r < 4; r++)
        ps_[wave][grp * 4 + r][jt * 16 + col16] = f2bf(p[jt][r]);
    __syncthreads();
#pragma unroll
    for (int ks2 = 0; ks2 < 2; ks2++) {
      bf16x8 a = *(const bf16x8*)&ps_[wave][col16][ks2 * 32 + grp * 8];
#pragma unroll
      for (int n = 0; n < 4; n++) {
        bf16x8 b = *(const bf16x8*)&vs_[n * 16 + col16][ks2 * 32 + grp * 8];
        o[n] = __builtin_amdgcn_mfma_f32_16x16x32_bf16(a, b, o[n], 0, 0, 0);
      }
    }
  }
  const int b = bh >> 3, h = bh & 7;
#pragma unroll
  for (int r = 0; r < 4; r++) {
    float inv = 1.f / l[r];
    int i = qb * 64 + wave * 16 + grp * 4 + r;
    float* op = seq_out + ((size_t)(b * T_) + i) * D_ + h * 64;
#pragma unroll
    for (int n = 0; n < 4; n++)
      op[n * 16 + col16] = o[n][r] * inv;
  }
}

// ------------- memory score via Gram-matrix scan -------------
// score_i = r_i^T M_i r_i,  M_i = sum_{j<i} decay^{i-j} u_j u_j^T  (21 sym comps)
// One block per bh. Phase A: chunk Gram partials. B: scan. C: per-row eval.
__constant__ int GA_[21] = {0,0,0,0,0,0,1,1,1,1,1,2,2,2,2,3,3,3,4,4,5};
__constant__ int GB_[21] = {0,1,2,3,4,5,1,2,3,4,5,2,3,4,5,3,4,5,4,5,5};

__global__ __launch_bounds__(512) void memscore2_kernel(
    const float* __restrict__ u, const float* __restrict__ r, float* __restrict__ score)
{
  const int bh = blockIdx.x;
  const int t = threadIdx.x;
  __shared__ float us[T_ * 6];        // 49152 B
  __shared__ float P[16][21];
  __shared__ float Mb[16][21];

  const float* ug = u + (size_t)bh * T_ * 6;
  for (int idx = t; idx < T_ * 6; idx += 512) us[idx] = ug[idx];
  __syncthreads();

  // Phase A: P[c][comp] = sum_{s=0..127} decay^(128-s) * u[c*128+s][a]*u[c*128+s][b]
  if (t < 336) {
    int c = t / 21, comp = t % 21;
    int a = GA_[comp], bb = GB_[comp];
    const float* ub = &us[c * 128 * 6];
    float p = 0.f, w = DECAY_;
    for (int s = 127; s >= 0; --s) {
      p = fmaf(w * ub[s * 6 + a], ub[s * 6 + bb], p);
      w *= DECAY_;
    }
    P[c][comp] = p;
  }
  __syncthreads();

  // Phase B: Mb[0]=0; Mb[c+1] = decay^128 * Mb[c] + P[c]
  if (t < 21) {
    float d128 = __powf(DECAY_, 128.f);
    float mcur = 0.f;
    for (int c = 0; c < 16; ++c) {
      Mb[c][t] = mcur;
      mcur = fmaf(d128, mcur, P[c][t]);
    }
  }
  __syncthreads();

  // Phase C: per row i
  const float invd = 1.0f / DECAY_;
  const int sbound = (t | 63) & 127;   // wave-uniform local-loop bound
  const int rel = t & 127;
#pragma unroll
  for (int rep = 0; rep < 4; ++rep) {
    int i = rep * 512 + t;
    int c = i >> 7, base = c << 7;
    const float* ri = r + ((size_t)bh * T_ + i) * 6;
    float r0 = ri[0], r1 = ri[1], r2 = ri[2], r3 = ri[3], r4 = ri[4], r5 = ri[5];
    float rv[6] = {r0, r1, r2, r3, r4, r5};
    // quadratic form r^T Mb[c] r
    float q = 0.f;
#pragma unroll
    for (int comp = 0; comp < 21; ++comp) {
      int a = GA_[comp], bb = GB_[comp];
      float mult = (a == bb) ? 1.f : 2.f;
      q = fmaf(Mb[c][comp] * mult, rv[a] * rv[bb], q);
    }
    float wl = __powf(DECAY_, (float)rel);
    float sum = q * wl;
    // local term: j in [base, i)
    float w = wl;
    const float* ub = &us[base * 6];
    for (int s = 0; s < sbound; ++s) {
      float d = r0 * ub[s * 6 + 0] + r1 * ub[s * 6 + 1] + r2 * ub[s * 6 + 2]
              + r3 * ub[s * 6 + 3] + r4 * ub[s * 6 + 4] + r5 * ub[s * 6 + 5];
      if (s < rel) sum = fmaf(w, d * d, sum);
      w *= invd;
    }
    score[(size_t)bh * T_ + i] = sum;
  }
}

// ------------- gating + combine -> bf16 seqo -------------
__global__ __launch_bounds__(256) void gate_combine_kernel(
    const float* __restrict__ score, const float* __restrict__ gate,
    const float* __restrict__ mem_scale, const float* __restrict__ mem_val,
    const float* __restrict__ seqo, ushort* __restrict__ seqo16)
{
  int bt = blockIdx.x;
  int b = bt / T_, t = bt % T_;
  __shared__ float g;
  if (threadIdx.x == 0) {
    float acc = 0.f;
#pragma unroll
    for (int h = 0; h < H_; h++) {
      float ms = score[((size_t)(b * H_ + h)) * T_ + t];
      float sg = 1.f / (1.f + __expf(-ms * mem_scale[h]));
      acc += sg * gate[(size_t)(b * T_ + t) * H_ + h];
    }
    g = acc * (1.0f / H_);
  }
  __syncthreads();
  float gv = g;
  size_t base = (size_t)(b * T_ + t) * D_;
  for (int d = threadIdx.x; d < D_; d += 256)
    seqo16[base + d] = f2bf(fmaf(gv, mem_val[base + d], seqo[base + d]));
}

extern "C" void kernel_launch(void* const* d_in, const int* in_sizes, int n_in,
                              void* d_out, int out_size, void* d_ws, size_t ws_size,
                              hipStream_t stream) {
  const float* x     = (const float*)d_in[0];
  const float* qkvw  = (const float*)d_in[1];
  const float* qkvb  = (const float*)d_in[2];
  const float* w1w   = (const float*)d_in[3];
  const float* w2w   = (const float*)d_in[4];
  const float* w1r   = (const float*)d_in[5];
  const float* w2r   = (const float*)d_in[6];
  const float* mvw   = (const float*)d_in[7];
  const float* mvb   = (const float*)d_in[8];
  const float* mgw   = (const float*)d_in[9];
  const float* mgb   = (const float*)d_in[10];
  const float* mscl  = (const float*)d_in[11];
  const float* ow    = (const float*)d_in[12];
  const float* ob    = (const float*)d_in[13];
  (void)in_sizes; (void)n_in; (void)out_size; (void)ws_size;

  float* f = (float*)d_ws;
  float* seqo   = f;                      // 2,097,152
  float* memval = seqo + 2097152;         // 2,097,152
  float* proj   = memval + 2097152;       // [4096][256] 1,048,576
  float* ul     = proj + 1048576;         // 196,608
  float* rl     = ul + 196608;            // 196,608
  float* gatep  = rl + 196608;            // 32,768
  float* msc    = gatep + 32768;          // 32,768
  ushort* x16    = (ushort*)(msc + 32768); // 2,097,152 (reused as seqo16 later)
  ushort* qkvw16 = x16 + 2097152;          // 786,432
  ushort* mvw16  = qkvw16 + 786432;        // 262,144
  ushort* ow16   = mvw16 + 262144;         // 262,144
  ushort* wcat16 = ow16 + 262144;          // 131,072
  ushort* q16    = wcat16 + 131072;        // 2,097,152
  ushort* k16    = q16 + QSZ;              // 2,097,152
  ushort* vt16   = k16 + QSZ;              // 2,097,152
  ushort* seqo16 = x16;

  const int M = B_ * T_;

  cast_bf16_kernel<<<dim3(1728), 256, 0, stream>>>(x, qkvw, mvw, ow,
                                                   w1w, w2w, w1r, w2r, mgw, x16);
  mfma_gemm<1><<<dim3(12, 32), 256, 0, stream>>>(x16, qkvw16, qkvb, q16, M, 3 * D_, D_);
  mfma_gemm<0><<<dim3(4, 32), 256, 0, stream>>>(x16, mvw16, mvb, memval, M, D_, D_);
  mfma_gemm<2><<<dim3(2, 32), 256, 0, stream>>>(x16, wcat16, nullptr, proj, M, 256, D_);
  lines_kernel<<<dim3(128), 256, 0, stream>>>(proj, mgb, ul, rl, gatep);
  attn_mfma_kernel<<<dim3(16 * (T_ / 64)), 256, 0, stream>>>(q16, k16, vt16, seqo);
  memscore2_kernel<<<dim3(B_ * H_), 512, 0, stream>>>(ul, rl, msc);
  gate_combine_kernel<<<dim3(B_ * T_), 256, 0, stream>>>(msc, gatep, mscl, memval,
                                                         seqo, seqo16);
  mfma_gemm<0><<<dim3(4, 32), 256, 0, stream>>>(seqo16, ow16, ob, d_out, M, D_, D_);
}